// Round 3
// baseline (1484.158 us; speedup 1.0000x reference)
//
#include <hip/hip_runtime.h>
#include <hip/hip_fp16.h>

// GraphEncoder: 3x ChebConv(K=6) + GroupNorm(8)/ReLU + dense readout.
// R8: R6's bucketA still eviction-bound (154MB WRITE = 2.4M lines @ 16.5G/s
//     = 146us; runs were ~1 line). Fix: 200 fat blocks (run ~20 edges) +
//     4B packed staging entries ((r&255)<<18 | c). ew compressed to 4B
//     column-only (w = -dis[i]*dis[c] factorized; -dis[i] hoisted per node,
//     dis[c] read per edge from L2-resident 640KB table) -> halves ew stream
//     in all 15 prop/horner passes and halves bucketB scatter writes.
// R6: two-phase bucket multisplit (fused deg hist); k_copyx zero-pads TxAll.
// R5: readout 2-stage split-K. R4: fp16 intermediates, fp32 accum.

#define NN 160000
#define EE 2560000
#define FD2 256
#define NBKT 625          // buckets of 256 rows each (NN = 625*256)
#define BCAPL 13          // bucket capacity 8192 = 1<<13 (mean fill 4096)
#define ABLK 200          // phase-A blocks
#define EPT 50            // edges per thread: 200*256*50 = EE exact

typedef __attribute__((ext_vector_type(8))) _Float16 half8;
typedef __attribute__((ext_vector_type(4))) float floatx4;

__device__ inline float2 h2f2(unsigned u) {
  __half2 h = __builtin_bit_cast(__half2, u);
  return __half22float2(h);
}
__device__ inline unsigned short f2h(float f) {
  return __builtin_bit_cast(unsigned short, __float2half_rn(f));
}
__device__ inline unsigned packh2(float a, float b) {
  return __builtin_bit_cast(unsigned, __floats2half2_rn(a, b));
}

// ----------------- CSR build -----------------
__global__ __launch_bounds__(256) void k_zero(int* __restrict__ p, int n) {
  int i = blockIdx.x * 256 + threadIdx.x;
  if (i < n) p[i] = 0;
}

__global__ __launch_bounds__(256) void k_binit(int* __restrict__ bcur) {
  int i = blockIdx.x * 256 + threadIdx.x;
  if (i < NBKT) bcur[i] = i << BCAPL;
}

// Phase A: stream edges; fused degree histogram + bucket multisplit.
// 200 blocks x 256 thr x 50 edges. Per-(block,bucket) staging runs are
// ~20 edges x 4B = 82B -> ~2.3 lines/run -> ~290K evictions (vs R6's 2.4M).
__global__ __launch_bounds__(256) void k_bucketA(const int* __restrict__ ei, int* __restrict__ deg,
                                                 int* __restrict__ bcur, unsigned* __restrict__ stg) {
  __shared__ int bcnt[NBKT];
  __shared__ int gbase[NBKT];
  int tid = threadIdx.x;
  for (int i = tid; i < NBKT; i += 256) bcnt[i] = 0;
  __syncthreads();
  int e0 = blockIdx.x * (256 * EPT);
  // pass 1: count (deg + per-block bucket counts)
#pragma unroll 5
  for (int k = 0; k < EPT; k++) {
    int e = e0 + k * 256 + tid;
    int rr = ei[e];
    atomicAdd(&deg[rr], 1);
    atomicAdd(&bcnt[rr >> 8], 1);
  }
  __syncthreads();
  // reserve one contiguous run per bucket for this block
  for (int i = tid; i < NBKT; i += 256) {
    gbase[i] = atomicAdd(&bcur[i], bcnt[i]);
    bcnt[i] = 0;
  }
  __syncthreads();
  // pass 2: scatter packed (r&255)<<18 | c  (c < 2^18, bucket implicit)
#pragma unroll 5
  for (int k = 0; k < EPT; k++) {
    int e = e0 + k * 256 + tid;
    int rr = ei[e];
    int c = ei[EE + e];
    int b = rr >> 8;
    int off = atomicAdd(&bcnt[b], 1);
    int pos = gbase[b] + off;
    if (pos < ((b + 1) << BCAPL))    // ~60-sigma overflow guard
      stg[pos] = ((unsigned)(rr & 255) << 18) | (unsigned)c;
  }
}

// Phase B: one workgroup per bucket; LDS row-cursors; 4B column-only scatter
// into a ~16KB L2-resident CSR window.
__global__ __launch_bounds__(256) void k_bucketB(const unsigned* __restrict__ stg, const int* __restrict__ bcur,
                                                 const int* __restrict__ rowStart, unsigned* __restrict__ ewc) {
  __shared__ int curs[256];
  int b = blockIdx.x;
  int tid = threadIdx.x;
  int r0 = b << 8;
  curs[tid] = rowStart[r0 + tid];
  __syncthreads();
  int cnt = bcur[b] - (b << BCAPL);
  if (cnt > (1 << BCAPL)) cnt = 1 << BCAPL;
  int base = b << BCAPL;
  for (int k = tid; k < cnt; k += 256) {
    unsigned u = stg[base + k];
    int rlow = u >> 18;
    int pos = atomicAdd(&curs[rlow], 1);
    ewc[pos] = u & 0x3FFFFu;
  }
}

__global__ __launch_bounds__(256) void k_dis(const int* __restrict__ deg, float* __restrict__ dis) {
  int i = blockIdx.x * 256 + threadIdx.x;
  if (i < NN) { int d = deg[i]; dis[i] = d > 0 ? rsqrtf((float)d) : 0.f; }
}

__global__ __launch_bounds__(256) void k_scan1(const int* __restrict__ deg, int* __restrict__ rowStart,
                                               int* __restrict__ bsum) {
  __shared__ int s[256];
  int tid = threadIdx.x;
  int i = blockIdx.x * 256 + tid;        // 625*256 = NN exact
  int v = deg[i];
  s[tid] = v;
  __syncthreads();
  for (int off = 1; off < 256; off <<= 1) {
    int t = (tid >= off) ? s[tid - off] : 0;
    __syncthreads();
    s[tid] += t;
    __syncthreads();
  }
  rowStart[i] = s[tid] - v;
  if (tid == 255) bsum[blockIdx.x] = s[255];
}

__global__ void k_scan2(int* __restrict__ bsum, int nb) {
  __shared__ int s[1024];
  int tid = threadIdx.x;
  int v = (tid < nb) ? bsum[tid] : 0;
  s[tid] = v;
  __syncthreads();
  for (int off = 1; off < 1024; off <<= 1) {
    int t = (tid >= off) ? s[tid - off] : 0;
    __syncthreads();
    s[tid] += t;
    __syncthreads();
  }
  if (tid < nb) bsum[tid] = s[tid] - v;
}

__global__ __launch_bounds__(256) void k_scan3(int* __restrict__ rowStart, const int* __restrict__ bsum) {
  int i = blockIdx.x * 256 + threadIdx.x;
  rowStart[i] += bsum[blockIdx.x];
  if (i == 0) rowStart[NN] = EE;
}

// ----------------- Layer 0 (cin=3) classic Chebyshev -----------------
// Writes full zero-padded 64B TxAll row per node (replaces k_zero pass).
__global__ __launch_bounds__(256) void k_copyx(const float* __restrict__ x, float* __restrict__ A,
                                               unsigned short* __restrict__ TxAll) {
  int i = blockIdx.x * 256 + threadIdx.x;     // node; grid 625*256 = NN exact
  if (i >= NN) return;
  float v0 = x[i * 3], v1 = x[i * 3 + 1], v2 = x[i * 3 + 2];
  A[i * 3] = v0; A[i * 3 + 1] = v1; A[i * 3 + 2] = v2;
  uint4* dst = reinterpret_cast<uint4*>(TxAll + (size_t)i * 32);
  uint4 z = make_uint4(0u, 0u, 0u, 0u);
  dst[0] = make_uint4(packh2(v0, v1), (unsigned)f2h(v2), 0u, 0u);
  dst[1] = z; dst[2] = z; dst[3] = z;
}

template <int MODE>   // 1: Tx1 = prop(Tx0); 2: Tnew = 2*prop(Tsrc) - Tdst (in place)
__global__ __launch_bounds__(256) void k_prop3(const float* __restrict__ Tsrc, float* __restrict__ Tdst,
                                               unsigned short* __restrict__ TxAll, int ks,
                                               const int* __restrict__ rowStart, const unsigned* __restrict__ ewc,
                                               const float* __restrict__ dis) {
  int i = blockIdx.x * 256 + threadIdx.x;
  if (i >= NN) return;
  float s0 = 0.f, s1 = 0.f, s2 = 0.f;
  int e = rowStart[i], e1 = rowStart[i + 1];
  for (; e + 3 < e1; e += 4) {
    unsigned c0 = ewc[e], c1 = ewc[e + 1], c2 = ewc[e + 2], c3 = ewc[e + 3];
    float w0 = dis[c0], w1 = dis[c1], w2 = dis[c2], w3 = dis[c3];
    s0 += w0 * Tsrc[c0 * 3] + w1 * Tsrc[c1 * 3] + w2 * Tsrc[c2 * 3] + w3 * Tsrc[c3 * 3];
    s1 += w0 * Tsrc[c0 * 3 + 1] + w1 * Tsrc[c1 * 3 + 1] + w2 * Tsrc[c2 * 3 + 1] + w3 * Tsrc[c3 * 3 + 1];
    s2 += w0 * Tsrc[c0 * 3 + 2] + w1 * Tsrc[c1 * 3 + 2] + w2 * Tsrc[c2 * 3 + 2] + w3 * Tsrc[c3 * 3 + 2];
  }
  for (; e < e1; e++) {
    unsigned c0 = ewc[e];
    float w0 = dis[c0];
    s0 += w0 * Tsrc[c0 * 3];
    s1 += w0 * Tsrc[c0 * 3 + 1];
    s2 += w0 * Tsrc[c0 * 3 + 2];
  }
  float di = -dis[i];
  float a0 = di * s0, a1 = di * s1, a2 = di * s2;
  if (MODE == 2) {
    a0 = 2.f * a0 - Tdst[i * 3];
    a1 = 2.f * a1 - Tdst[i * 3 + 1];
    a2 = 2.f * a2 - Tdst[i * 3 + 2];
  }
  Tdst[i * 3] = a0; Tdst[i * 3 + 1] = a1; Tdst[i * 3 + 2] = a2;
  unsigned short* tp = TxAll + i * 32 + ks * 3;
  tp[0] = f2h(a0); tp[1] = f2h(a1); tp[2] = f2h(a2);
}

// W0 (18 x 128) -> transposed padded fp16 (128 x 32)
__global__ __launch_bounds__(256) void k_padW0(const float* __restrict__ W0, unsigned short* __restrict__ Bt) {
  int idx = blockIdx.x * 256 + threadIdx.x;   // 128*32
  if (idx >= 128 * 32) return;
  int co = idx >> 5, t = idx & 31;
  Bt[co * 32 + t] = (t < 18) ? f2h(W0[t * 128 + co]) : (unsigned short)0;
}

// C_j = sum_k a[k][j] W_k, written TRANSPOSED fp16: Bt[(j*COUT+co)*CIN + ci]
template <int CIN, int COUT>
__global__ __launch_bounds__(256) void k_combine(const float* __restrict__ W, unsigned short* __restrict__ Bt) {
  int idx = blockIdx.x * 256 + threadIdx.x;
  if (idx >= CIN * 6 * COUT) return;
  int co = idx % COUT;
  int j  = (idx / COUT) % 6;
  int ci = idx / (6 * COUT);
  float c0, c1, c2, c3, c4, c5;
  switch (j) {
    case 0:  c0 = 1;  c1 = 0;  c2 = -1; c3 = 0;   c4 = 1;  c5 = 0;   break;
    case 1:  c0 = 0;  c1 = 1;  c2 = 0;  c3 = -3;  c4 = 0;  c5 = 5;   break;
    case 2:  c0 = 0;  c1 = 0;  c2 = 2;  c3 = 0;   c4 = -8; c5 = 0;   break;
    case 3:  c0 = 0;  c1 = 0;  c2 = 0;  c3 = 4;   c4 = 0;  c5 = -20; break;
    case 4:  c0 = 0;  c1 = 0;  c2 = 0;  c3 = 0;   c4 = 8;  c5 = 0;   break;
    default: c0 = 0;  c1 = 0;  c2 = 0;  c3 = 0;   c4 = 0;  c5 = 16;  break;
  }
  float s = 0.f;
  s += c0 * W[(0 * CIN + ci) * COUT + co];
  s += c1 * W[(1 * CIN + ci) * COUT + co];
  s += c2 * W[(2 * CIN + ci) * COUT + co];
  s += c3 * W[(3 * CIN + ci) * COUT + co];
  s += c4 * W[(4 * CIN + ci) * COUT + co];
  s += c5 * W[(5 * CIN + ci) * COUT + co];
  Bt[(j * COUT + co) * CIN + ci] = f2h(s);
}

// ----------------- MFMA f16 GEMM: (N x KDIM) @ Bt(ncol x KDIM)^T -> Y fp16 ----------
template <int KDIM, int COUT>
__global__ __launch_bounds__(256) void k_gemm(const unsigned short* __restrict__ A,
                                              const unsigned short* __restrict__ Bt,
                                              unsigned short* __restrict__ Y) {
  constexpr int KP = KDIM + 8;
  __shared__ unsigned short As[64 * KP];
  __shared__ unsigned short Bs[64 * KP];
  int i0 = blockIdx.x * 64;
  int c0 = blockIdx.y * 64;
  for (int idx = threadIdx.x; idx < 64 * (KDIM / 8); idx += 256) {
    int row = idx / (KDIM / 8), seg = idx % (KDIM / 8);
    uint4 v = ((const uint4*)A)[(size_t)(i0 + row) * (KDIM / 8) + seg];
    *reinterpret_cast<uint4*>(&As[row * KP + seg * 8]) = v;
  }
  for (int idx = threadIdx.x; idx < 64 * (KDIM / 8); idx += 256) {
    int row = idx / (KDIM / 8), seg = idx % (KDIM / 8);
    uint4 v = ((const uint4*)Bt)[(size_t)(c0 + row) * (KDIM / 8) + seg];
    *reinterpret_cast<uint4*>(&Bs[row * KP + seg * 8]) = v;
  }
  __syncthreads();
  int w = threadIdx.x >> 6, lane = threadIdx.x & 63;
  int mn = lane & 15, q = lane >> 4;
  floatx4 acc[4];
#pragma unroll
  for (int cb = 0; cb < 4; cb++) acc[cb] = {0.f, 0.f, 0.f, 0.f};
#pragma unroll
  for (int ks = 0; ks < KDIM / 32; ks++) {
    half8 af = *reinterpret_cast<const half8*>(&As[(16 * w + mn) * KP + ks * 32 + q * 8]);
#pragma unroll
    for (int cb = 0; cb < 4; cb++) {
      half8 bf = *reinterpret_cast<const half8*>(&Bs[(cb * 16 + mn) * KP + ks * 32 + q * 8]);
      acc[cb] = __builtin_amdgcn_mfma_f32_16x16x32_f16(af, bf, acc[cb], 0, 0, 0);
    }
  }
  // C/D layout: col = lane&15, row = (lane>>4)*4 + reg  [m89; dtype-independent]
#pragma unroll
  for (int cb = 0; cb < 4; cb++) {
    int jc = c0 + cb * 16 + mn;
    int slice = jc / COUT, cc = jc % COUT;
    unsigned short* dst = Y + (size_t)slice * NN * COUT + cc;
#pragma unroll
    for (int r = 0; r < 4; r++) {
      int i = i0 + 16 * w + q * 4 + r;
      dst[(size_t)i * COUT] = f2h(acc[cb][r]);
    }
  }
}

// ----------------- Horner prop step (fp16): Ydst += L * Ysrc, in cout space ---------
// w_e = -dis[i]*dis[c]; -dis[i] hoisted out of the edge loop.
template <int CPN>
__global__ __launch_bounds__(256) void k_horner(const unsigned* __restrict__ Ysrc, unsigned* __restrict__ Ydst,
                                                const int* __restrict__ rowStart, const unsigned* __restrict__ ewc,
                                                const float* __restrict__ dis) {
  int t = blockIdx.x * 256 + threadIdx.x;
  int i = t / CPN;
  int cp = t % CPN;
  float2 a = h2f2(Ydst[(size_t)i * CPN + cp]);
  float s0 = 0.f, s1 = 0.f;
  int e = rowStart[i], e1 = rowStart[i + 1];
  for (; e + 7 < e1; e += 8) {
    unsigned cc[8];
    float wv[8];
    unsigned u[8];
#pragma unroll
    for (int k = 0; k < 8; k++) cc[k] = ewc[e + k];
#pragma unroll
    for (int k = 0; k < 8; k++) wv[k] = dis[cc[k]];
#pragma unroll
    for (int k = 0; k < 8; k++) u[k] = Ysrc[(size_t)cc[k] * CPN + cp];
#pragma unroll
    for (int k = 0; k < 8; k++) {
      float2 f = h2f2(u[k]);
      s0 += wv[k] * f.x;
      s1 += wv[k] * f.y;
    }
  }
  for (; e < e1; e++) {
    unsigned c0 = ewc[e];
    float w0 = dis[c0];
    float2 f0 = h2f2(Ysrc[(size_t)c0 * CPN + cp]);
    s0 += w0 * f0.x;
    s1 += w0 * f0.y;
  }
  float di = -dis[i];
  Ydst[(size_t)i * CPN + cp] = packh2(a.x + di * s0, a.y + di * s1);
}

// ----------------- GroupNorm(8) + bias + ReLU (fp16 in/out) -----------------
template <int CPG>
__global__ __launch_bounds__(256) void k_gn(const unsigned short* __restrict__ src, const float* __restrict__ bias,
                                            const float* __restrict__ gamma, const float* __restrict__ beta,
                                            unsigned short* __restrict__ dst) {
  constexpr int C = CPG * 8;
  int t = blockIdx.x * 256 + threadIdx.x;   // (node, group); grid 5000*256 = NN*8 exact
  int i = t >> 3, g = t & 7;
  float v[CPG];
  const unsigned* p = reinterpret_cast<const unsigned*>(src + (size_t)i * C + g * CPG);
#pragma unroll
  for (int q = 0; q < CPG / 2; q++) {
    float2 f = h2f2(p[q]);
    v[2 * q] = f.x; v[2 * q + 1] = f.y;
  }
  float mean = 0.f;
#pragma unroll
  for (int c = 0; c < CPG; c++) { v[c] += bias[g * CPG + c]; mean += v[c]; }
  mean *= (1.f / CPG);
  float var = 0.f;
#pragma unroll
  for (int c = 0; c < CPG; c++) { float d = v[c] - mean; var += d * d; }
  var *= (1.f / CPG);
  float rs = rsqrtf(var + 1e-5f);
  unsigned* dp = reinterpret_cast<unsigned*>(dst + (size_t)i * C + g * CPG);
#pragma unroll
  for (int q = 0; q < CPG / 2; q++) {
    float o0 = fmaxf((v[2 * q] - mean) * rs * gamma[g * CPG + 2 * q] + beta[g * CPG + 2 * q], 0.f);
    float o1 = fmaxf((v[2 * q + 1] - mean) * rs * gamma[g * CPG + 2 * q + 1] + beta[g * CPG + 2 * q + 1], 0.f);
    dp[q] = packh2(o0, o1);
  }
}

// ----------------- Readout: (16 x 320000) @ (320000 x 128), 2-stage split-K ----------
__global__ __launch_bounds__(256) void k_final1(const unsigned short* __restrict__ h3,
                                                const float* __restrict__ Wl,
                                                float* __restrict__ part) {
  __shared__ float hs[16 * FD2];     // 16 KB
  __shared__ float red[2048];        // 8 KB
  int d0 = blockIdx.x * FD2;
  const unsigned* h3u = reinterpret_cast<const unsigned*>(h3);
  for (int idx = threadIdx.x; idx < 16 * (FD2 / 2); idx += 256) {
    int b = idx / (FD2 / 2), dq = idx % (FD2 / 2);
    float2 f = h2f2(h3u[(size_t)b * 160000 + (d0 >> 1) + dq]);
    hs[b * FD2 + 2 * dq] = f.x;
    hs[b * FD2 + 2 * dq + 1] = f.y;
  }
  __syncthreads();
  int w = threadIdx.x >> 6, lane = threadIdx.x & 63;
  float a0[16], a1[16];
#pragma unroll
  for (int b = 0; b < 16; b++) { a0[b] = 0.f; a1[b] = 0.f; }
  const float* wp = Wl + (size_t)(d0 + w * (FD2 / 4)) * 128 + 2 * lane;
#pragma unroll 2
  for (int r = 0; r < FD2 / 4; r++) {
    float2 wv = *reinterpret_cast<const float2*>(wp + (size_t)r * 128);
    int row = w * (FD2 / 4) + r;
#pragma unroll
    for (int b = 0; b < 16; b++) {
      float h = hs[b * FD2 + row];
      a0[b] += wv.x * h;
      a1[b] += wv.y * h;
    }
  }
  float2* red2 = reinterpret_cast<float2*>(red);
  for (int ww = 0; ww < 4; ww++) {
    if (w == ww) {
#pragma unroll
      for (int b = 0; b < 16; b++) {
        if (ww == 0) {
          red2[b * 64 + lane] = make_float2(a0[b], a1[b]);
        } else {
          float2 r2 = red2[b * 64 + lane];
          r2.x += a0[b]; r2.y += a1[b];
          red2[b * 64 + lane] = r2;
        }
      }
    }
    __syncthreads();
  }
  for (int i = threadIdx.x; i < 2048; i += 256)
    part[(size_t)blockIdx.x * 2048 + i] = red[i];
}

// Stage 2: 8 blocks x 256 threads; each thread reduces 1250 partials + bias.
__global__ __launch_bounds__(256) void k_final2(const float* __restrict__ part, const float* __restrict__ bl,
                                                float* __restrict__ out) {
  int o = blockIdx.x * 256 + threadIdx.x;   // 0..2047
  float s = bl[o & 127];
#pragma unroll 10
  for (int p = 0; p < 1250; p++) s += part[(size_t)p * 2048 + o];
  out[o] = s;
}

// ----------------- launcher -----------------
extern "C" void kernel_launch(void* const* d_in, const int* in_sizes, int n_in,
                              void* d_out, int out_size, void* d_ws, size_t ws_size,
                              hipStream_t stream) {
  const float* x   = (const float*)d_in[0];
  const int*   ei  = (const int*)d_in[1];   // harness stages ALL integer inputs as int32
  const float* W0  = (const float*)d_in[2];
  const float* b0  = (const float*)d_in[3];
  const float* g0  = (const float*)d_in[4];
  const float* be0 = (const float*)d_in[5];
  const float* W1  = (const float*)d_in[6];
  const float* b1  = (const float*)d_in[7];
  const float* g1  = (const float*)d_in[8];
  const float* be1 = (const float*)d_in[9];
  const float* W2  = (const float*)d_in[10];
  const float* b2  = (const float*)d_in[11];
  const float* g2  = (const float*)d_in[12];
  const float* be2 = (const float*)d_in[13];
  const float* Wl  = (const float*)d_in[14];
  const float* bl  = (const float*)d_in[15];
  float* out = (float*)d_out;
  (void)in_sizes; (void)n_in; (void)out_size; (void)ws_size;

  char* pw = (char*)d_ws;
  auto carve = [&](size_t bytes) -> void* {
    void* r = (void*)pw;
    pw += (bytes + 255) & ~(size_t)255;
    return r;
  };
  int*            deg      = (int*)   carve((size_t)NN * 4);
  int*            bcur     = (int*)   carve((size_t)NBKT * 4);
  int*            rowStart = (int*)   carve((size_t)(NN + 1) * 4);
  int*            bsum     = (int*)   carve(1024 * 4);
  float*          dis      = (float*) carve((size_t)NN * 4);
  unsigned*       ewc      = (unsigned*)carve((size_t)EE * 4);
  unsigned short* Cwt      = (unsigned short*)carve((size_t)384 * 128 * 2);
  unsigned short* TxAll    = (unsigned short*)carve((size_t)NN * 32 * 2);
  float*          A3       = (float*) carve((size_t)NN * 3 * 4);
  float*          B3       = (float*) carve((size_t)NN * 3 * 4);
  unsigned short* Hbuf     = (unsigned short*)carve((size_t)NN * 128 * 2);
  unsigned short* Ybuf     = (unsigned short*)carve((size_t)NN * 384 * 2);
  float*          part     = (float*) carve((size_t)1250 * 2048 * 4);
  unsigned*       stg      = (unsigned*)Ybuf;   // (625<<13)*4B = 20.5MB; Ybuf dead until layer0 GEMM

  // ---- CSR build (two-phase multisplit, packed 4B staging) ----
  k_zero<<<625, 256, 0, stream>>>(deg, NN);
  k_binit<<<3, 256, 0, stream>>>(bcur);
  k_bucketA<<<ABLK, 256, 0, stream>>>(ei, deg, bcur, stg);
  k_dis<<<625, 256, 0, stream>>>(deg, dis);
  k_scan1<<<625, 256, 0, stream>>>(deg, rowStart, bsum);
  k_scan2<<<1, 1024, 0, stream>>>(bsum, 625);
  k_scan3<<<625, 256, 0, stream>>>(rowStart, bsum);
  k_bucketB<<<NBKT, 256, 0, stream>>>(stg, bcur, rowStart, ewc);

  // ---- Layer 0 (3 -> 128): classic Chebyshev, TxAll (NN x 32 fp16, zero-pad) ----
  k_copyx<<<625, 256, 0, stream>>>(x, A3, TxAll);
  k_prop3<1><<<625, 256, 0, stream>>>(A3, B3, TxAll, 1, rowStart, ewc, dis);
  k_prop3<2><<<625, 256, 0, stream>>>(B3, A3, TxAll, 2, rowStart, ewc, dis);
  k_prop3<2><<<625, 256, 0, stream>>>(A3, B3, TxAll, 3, rowStart, ewc, dis);
  k_prop3<2><<<625, 256, 0, stream>>>(B3, A3, TxAll, 4, rowStart, ewc, dis);
  k_prop3<2><<<625, 256, 0, stream>>>(A3, B3, TxAll, 5, rowStart, ewc, dis);
  k_padW0<<<16, 256, 0, stream>>>(W0, Cwt);
  k_gemm<32, 128><<<dim3(2500, 2), 256, 0, stream>>>(TxAll, Cwt, Ybuf);
  k_gn<16><<<5000, 256, 0, stream>>>(Ybuf, b0, g0, be0, Hbuf);

  // ---- Layer 1 (128 -> 64): one MFMA GEMM + 5 Horner props in cout space ----
  k_combine<128, 64><<<192, 256, 0, stream>>>(W1, Cwt);
  k_gemm<128, 64><<<dim3(2500, 6), 256, 0, stream>>>(Hbuf, Cwt, Ybuf);
  for (int j = 4; j >= 0; j--)
    k_horner<32><<<20000, 256, 0, stream>>>((unsigned*)(Ybuf + (size_t)(j + 1) * NN * 64),
                                            (unsigned*)(Ybuf + (size_t)j * NN * 64), rowStart, ewc, dis);
  k_gn<8><<<5000, 256, 0, stream>>>(Ybuf, b1, g1, be1, Hbuf);

  // ---- Layer 2 (64 -> 32) ----
  k_combine<64, 32><<<48, 256, 0, stream>>>(W2, Cwt);
  k_gemm<64, 32><<<dim3(2500, 3), 256, 0, stream>>>(Hbuf, Cwt, Ybuf);
  for (int j = 4; j >= 0; j--)
    k_horner<16><<<10000, 256, 0, stream>>>((unsigned*)(Ybuf + (size_t)(j + 1) * NN * 32),
                                            (unsigned*)(Ybuf + (size_t)j * NN * 32), rowStart, ewc, dis);
  k_gn<4><<<5000, 256, 0, stream>>>(Ybuf, b2, g2, be2, Hbuf);

  // ---- Readout: 2-stage split-K ----
  k_final1<<<1250, 256, 0, stream>>>(Hbuf, Wl, part);
  k_final2<<<8, 256, 0, stream>>>(part, bl, out);
}

// Round 4
// 1280.947 us; speedup vs baseline: 1.1586x; 1.1586x over previous
//
#include <hip/hip_runtime.h>
#include <hip/hip_fp16.h>

// GraphEncoder: 3x ChebConv(K=6) + GroupNorm(8)/ReLU + dense readout.
// R9: R8 post-mortem: (a) bucketA's 109MB WRITE was the 2.56M global deg
//     atomics (~40B memory-side RMW each), not staging; (b) per-edge dis[c]
//     gather in horner was 16x-redundant -> +114us. Fix: degrees computed
//     PER BUCKET with LDS-only atomics (bucket b holds all edges of its 256
//     rows) -> no global deg/scan/dis kernels; rowStart from a 625-entry
//     bucket scan. ew reverted to packed 8B (c,w) - R6's proven prop path.
// R6: two-phase bucket multisplit; k_copyx zero-pads TxAll.
// R5: readout 2-stage split-K. R4: fp16 intermediates, fp32 accum.

#define NN 160000
#define EE 2560000
#define FD2 256
#define NBKT 625          // buckets of 256 rows each (NN = 625*256)
#define BCAPL 13          // bucket capacity 8192 = 1<<13 (mean fill 4096)
#define ABLK 500          // phase-A blocks
#define EPT 20            // edges per thread: 500*256*20 = EE exact

typedef __attribute__((ext_vector_type(8))) _Float16 half8;
typedef __attribute__((ext_vector_type(4))) float floatx4;

__device__ inline float2 h2f2(unsigned u) {
  __half2 h = __builtin_bit_cast(__half2, u);
  return __half22float2(h);
}
__device__ inline unsigned short f2h(float f) {
  return __builtin_bit_cast(unsigned short, __float2half_rn(f));
}
__device__ inline unsigned packh2(float a, float b) {
  return __builtin_bit_cast(unsigned, __floats2half2_rn(a, b));
}

// ----------------- CSR build (atomic-free-global multisplit) -----------------
__global__ __launch_bounds__(256) void k_binit(int* __restrict__ bcur) {
  int i = blockIdx.x * 256 + threadIdx.x;
  if (i < NBKT) bcur[i] = i << BCAPL;
}

// Phase A: 500 blocks x 256 thr x 20 edges. LDS bucket histogram, reserve
// one contiguous staging run per (block,bucket), scatter packed 4B entries
// (r&255)<<18 | c. Global atomics: only 625 bcur adds per block.
__global__ __launch_bounds__(256) void k_bucketA(const int* __restrict__ ei,
                                                 int* __restrict__ bcur, unsigned* __restrict__ stg) {
  __shared__ int bcnt[NBKT];
  __shared__ int gbase[NBKT];
  int tid = threadIdx.x;
  for (int i = tid; i < NBKT; i += 256) bcnt[i] = 0;
  __syncthreads();
  int r[EPT];
  int e0 = blockIdx.x * (256 * EPT);
#pragma unroll
  for (int k = 0; k < EPT; k++) {
    int e = e0 + k * 256 + tid;
    r[k] = ei[e];
    atomicAdd(&bcnt[r[k] >> 8], 1);
  }
  __syncthreads();
  for (int i = tid; i < NBKT; i += 256) {
    gbase[i] = atomicAdd(&bcur[i], bcnt[i]);
    bcnt[i] = 0;
  }
  __syncthreads();
#pragma unroll
  for (int k = 0; k < EPT; k++) {
    int e = e0 + k * 256 + tid;
    int c = ei[EE + e];
    int b = r[k] >> 8;
    int off = atomicAdd(&bcnt[b], 1);
    int pos = gbase[b] + off;
    if (pos < ((b + 1) << BCAPL))    // ~60-sigma overflow guard
      stg[pos] = ((unsigned)(r[k] & 255) << 18) | (unsigned)c;
  }
}

// Exclusive scan of the 625 bucket totals -> bucket base offsets in ew.
__global__ void k_bktscan(const int* __restrict__ bcur, int* __restrict__ bbase,
                          int* __restrict__ rowStart) {
  __shared__ int s[1024];
  int tid = threadIdx.x;
  int tot = 0;
  if (tid < NBKT) {
    tot = bcur[tid] - (tid << BCAPL);
    if (tot > (1 << BCAPL)) tot = 1 << BCAPL;
  }
  s[tid] = tot;
  __syncthreads();
  for (int off = 1; off < 1024; off <<= 1) {
    int t = (tid >= off) ? s[tid - off] : 0;
    __syncthreads();
    s[tid] += t;
    __syncthreads();
  }
  if (tid < NBKT) bbase[tid] = s[tid] - tot;
  if (tid == 0) rowStart[NN] = EE;
}

// Phase B1: per bucket: LDS degree histogram of its 256 rows + LDS scan ->
// rowStart and dis for those rows. All edges of the rows are in this bucket.
__global__ __launch_bounds__(256) void k_bucketB1(const unsigned* __restrict__ stg, const int* __restrict__ bcur,
                                                  const int* __restrict__ bbase, int* __restrict__ rowStart,
                                                  float* __restrict__ dis) {
  __shared__ int degl[256];
  __shared__ int s[256];
  int b = blockIdx.x;
  int tid = threadIdx.x;
  degl[tid] = 0;
  __syncthreads();
  int cnt = bcur[b] - (b << BCAPL);
  if (cnt > (1 << BCAPL)) cnt = 1 << BCAPL;
  int base = b << BCAPL;
  for (int k = tid; k < cnt; k += 256)
    atomicAdd(&degl[stg[base + k] >> 18], 1);
  __syncthreads();
  int d = degl[tid];
  s[tid] = d;
  __syncthreads();
  for (int off = 1; off < 256; off <<= 1) {
    int t = (tid >= off) ? s[tid - off] : 0;
    __syncthreads();
    s[tid] += t;
    __syncthreads();
  }
  int r0 = b << 8;
  rowStart[r0 + tid] = bbase[b] + s[tid] - d;
  dis[r0 + tid] = d > 0 ? rsqrtf((float)d) : 0.f;
}

// Phase B2: per bucket: LDS row-cursors; compute w once per edge; 8B (c,w)
// scatter into the bucket's ~32KB L2-resident CSR window.
__global__ __launch_bounds__(256) void k_bucketB2(const unsigned* __restrict__ stg, const int* __restrict__ bcur,
                                                  const int* __restrict__ rowStart, const float* __restrict__ dis,
                                                  int2* __restrict__ ew) {
  __shared__ int curs[256];
  __shared__ float disl[256];
  int b = blockIdx.x;
  int tid = threadIdx.x;
  int r0 = b << 8;
  curs[tid] = rowStart[r0 + tid];
  disl[tid] = dis[r0 + tid];
  __syncthreads();
  int cnt = bcur[b] - (b << BCAPL);
  if (cnt > (1 << BCAPL)) cnt = 1 << BCAPL;
  int base = b << BCAPL;
  for (int k = tid; k < cnt; k += 256) {
    unsigned u = stg[base + k];
    int rlow = u >> 18;
    int c = u & 0x3FFFFu;
    int pos = atomicAdd(&curs[rlow], 1);
    float w = -disl[rlow] * dis[c];
    ew[pos] = make_int2(c, __float_as_int(w));
  }
}

// ----------------- Layer 0 (cin=3) classic Chebyshev -----------------
// Writes full zero-padded 64B TxAll row per node.
__global__ __launch_bounds__(256) void k_copyx(const float* __restrict__ x, float* __restrict__ A,
                                               unsigned short* __restrict__ TxAll) {
  int i = blockIdx.x * 256 + threadIdx.x;     // node; grid 625*256 = NN exact
  if (i >= NN) return;
  float v0 = x[i * 3], v1 = x[i * 3 + 1], v2 = x[i * 3 + 2];
  A[i * 3] = v0; A[i * 3 + 1] = v1; A[i * 3 + 2] = v2;
  uint4* dst = reinterpret_cast<uint4*>(TxAll + (size_t)i * 32);
  uint4 z = make_uint4(0u, 0u, 0u, 0u);
  dst[0] = make_uint4(packh2(v0, v1), (unsigned)f2h(v2), 0u, 0u);
  dst[1] = z; dst[2] = z; dst[3] = z;
}

template <int MODE>   // 1: Tx1 = prop(Tx0); 2: Tnew = 2*prop(Tsrc) - Tdst (in place)
__global__ __launch_bounds__(256) void k_prop3(const float* __restrict__ Tsrc, float* __restrict__ Tdst,
                                               unsigned short* __restrict__ TxAll, int ks,
                                               const int* __restrict__ rowStart, const int2* __restrict__ ew) {
  int i = blockIdx.x * 256 + threadIdx.x;
  if (i >= NN) return;
  float a0 = 0.f, a1 = 0.f, a2 = 0.f;
  int e = rowStart[i], e1 = rowStart[i + 1];
  for (; e + 3 < e1; e += 4) {
    int2 p0 = ew[e], p1 = ew[e + 1], p2 = ew[e + 2], p3 = ew[e + 3];
    float w0 = __int_as_float(p0.y), w1 = __int_as_float(p1.y);
    float w2 = __int_as_float(p2.y), w3 = __int_as_float(p3.y);
    a0 += w0 * Tsrc[p0.x * 3] + w1 * Tsrc[p1.x * 3] + w2 * Tsrc[p2.x * 3] + w3 * Tsrc[p3.x * 3];
    a1 += w0 * Tsrc[p0.x * 3 + 1] + w1 * Tsrc[p1.x * 3 + 1] + w2 * Tsrc[p2.x * 3 + 1] + w3 * Tsrc[p3.x * 3 + 1];
    a2 += w0 * Tsrc[p0.x * 3 + 2] + w1 * Tsrc[p1.x * 3 + 2] + w2 * Tsrc[p2.x * 3 + 2] + w3 * Tsrc[p3.x * 3 + 2];
  }
  for (; e < e1; e++) {
    int2 p0 = ew[e];
    float w0 = __int_as_float(p0.y);
    a0 += w0 * Tsrc[p0.x * 3];
    a1 += w0 * Tsrc[p0.x * 3 + 1];
    a2 += w0 * Tsrc[p0.x * 3 + 2];
  }
  if (MODE == 2) {
    a0 = 2.f * a0 - Tdst[i * 3];
    a1 = 2.f * a1 - Tdst[i * 3 + 1];
    a2 = 2.f * a2 - Tdst[i * 3 + 2];
  }
  Tdst[i * 3] = a0; Tdst[i * 3 + 1] = a1; Tdst[i * 3 + 2] = a2;
  unsigned short* tp = TxAll + i * 32 + ks * 3;
  tp[0] = f2h(a0); tp[1] = f2h(a1); tp[2] = f2h(a2);
}

// W0 (18 x 128) -> transposed padded fp16 (128 x 32)
__global__ __launch_bounds__(256) void k_padW0(const float* __restrict__ W0, unsigned short* __restrict__ Bt) {
  int idx = blockIdx.x * 256 + threadIdx.x;   // 128*32
  if (idx >= 128 * 32) return;
  int co = idx >> 5, t = idx & 31;
  Bt[co * 32 + t] = (t < 18) ? f2h(W0[t * 128 + co]) : (unsigned short)0;
}

// C_j = sum_k a[k][j] W_k, written TRANSPOSED fp16: Bt[(j*COUT+co)*CIN + ci]
template <int CIN, int COUT>
__global__ __launch_bounds__(256) void k_combine(const float* __restrict__ W, unsigned short* __restrict__ Bt) {
  int idx = blockIdx.x * 256 + threadIdx.x;
  if (idx >= CIN * 6 * COUT) return;
  int co = idx % COUT;
  int j  = (idx / COUT) % 6;
  int ci = idx / (6 * COUT);
  float c0, c1, c2, c3, c4, c5;
  switch (j) {
    case 0:  c0 = 1;  c1 = 0;  c2 = -1; c3 = 0;   c4 = 1;  c5 = 0;   break;
    case 1:  c0 = 0;  c1 = 1;  c2 = 0;  c3 = -3;  c4 = 0;  c5 = 5;   break;
    case 2:  c0 = 0;  c1 = 0;  c2 = 2;  c3 = 0;   c4 = -8; c5 = 0;   break;
    case 3:  c0 = 0;  c1 = 0;  c2 = 0;  c3 = 4;   c4 = 0;  c5 = -20; break;
    case 4:  c0 = 0;  c1 = 0;  c2 = 0;  c3 = 0;   c4 = 8;  c5 = 0;   break;
    default: c0 = 0;  c1 = 0;  c2 = 0;  c3 = 0;   c4 = 0;  c5 = 16;  break;
  }
  float s = 0.f;
  s += c0 * W[(0 * CIN + ci) * COUT + co];
  s += c1 * W[(1 * CIN + ci) * COUT + co];
  s += c2 * W[(2 * CIN + ci) * COUT + co];
  s += c3 * W[(3 * CIN + ci) * COUT + co];
  s += c4 * W[(4 * CIN + ci) * COUT + co];
  s += c5 * W[(5 * CIN + ci) * COUT + co];
  Bt[(j * COUT + co) * CIN + ci] = f2h(s);
}

// ----------------- MFMA f16 GEMM: (N x KDIM) @ Bt(ncol x KDIM)^T -> Y fp16 ----------
template <int KDIM, int COUT>
__global__ __launch_bounds__(256) void k_gemm(const unsigned short* __restrict__ A,
                                              const unsigned short* __restrict__ Bt,
                                              unsigned short* __restrict__ Y) {
  constexpr int KP = KDIM + 8;
  __shared__ unsigned short As[64 * KP];
  __shared__ unsigned short Bs[64 * KP];
  int i0 = blockIdx.x * 64;
  int c0 = blockIdx.y * 64;
  for (int idx = threadIdx.x; idx < 64 * (KDIM / 8); idx += 256) {
    int row = idx / (KDIM / 8), seg = idx % (KDIM / 8);
    uint4 v = ((const uint4*)A)[(size_t)(i0 + row) * (KDIM / 8) + seg];
    *reinterpret_cast<uint4*>(&As[row * KP + seg * 8]) = v;
  }
  for (int idx = threadIdx.x; idx < 64 * (KDIM / 8); idx += 256) {
    int row = idx / (KDIM / 8), seg = idx % (KDIM / 8);
    uint4 v = ((const uint4*)Bt)[(size_t)(c0 + row) * (KDIM / 8) + seg];
    *reinterpret_cast<uint4*>(&Bs[row * KP + seg * 8]) = v;
  }
  __syncthreads();
  int w = threadIdx.x >> 6, lane = threadIdx.x & 63;
  int mn = lane & 15, q = lane >> 4;
  floatx4 acc[4];
#pragma unroll
  for (int cb = 0; cb < 4; cb++) acc[cb] = {0.f, 0.f, 0.f, 0.f};
#pragma unroll
  for (int ks = 0; ks < KDIM / 32; ks++) {
    half8 af = *reinterpret_cast<const half8*>(&As[(16 * w + mn) * KP + ks * 32 + q * 8]);
#pragma unroll
    for (int cb = 0; cb < 4; cb++) {
      half8 bf = *reinterpret_cast<const half8*>(&Bs[(cb * 16 + mn) * KP + ks * 32 + q * 8]);
      acc[cb] = __builtin_amdgcn_mfma_f32_16x16x32_f16(af, bf, acc[cb], 0, 0, 0);
    }
  }
  // C/D layout: col = lane&15, row = (lane>>4)*4 + reg  [m89; dtype-independent]
#pragma unroll
  for (int cb = 0; cb < 4; cb++) {
    int jc = c0 + cb * 16 + mn;
    int slice = jc / COUT, cc = jc % COUT;
    unsigned short* dst = Y + (size_t)slice * NN * COUT + cc;
#pragma unroll
    for (int r = 0; r < 4; r++) {
      int i = i0 + 16 * w + q * 4 + r;
      dst[(size_t)i * COUT] = f2h(acc[cb][r]);
    }
  }
}

// ----------------- Horner prop step (fp16): Ydst += L * Ysrc, in cout space ---------
template <int CPN>
__global__ __launch_bounds__(256) void k_horner(const unsigned* __restrict__ Ysrc, unsigned* __restrict__ Ydst,
                                                const int* __restrict__ rowStart, const int2* __restrict__ ew) {
  int t = blockIdx.x * 256 + threadIdx.x;
  int i = t / CPN;
  int cp = t % CPN;
  float2 a = h2f2(Ydst[(size_t)i * CPN + cp]);
  float acc0 = a.x, acc1 = a.y;
  int e = rowStart[i], e1 = rowStart[i + 1];
  for (; e + 7 < e1; e += 8) {
    int2 p[8];
    unsigned u[8];
#pragma unroll
    for (int k = 0; k < 8; k++) p[k] = ew[e + k];
#pragma unroll
    for (int k = 0; k < 8; k++) u[k] = Ysrc[(size_t)p[k].x * CPN + cp];
#pragma unroll
    for (int k = 0; k < 8; k++) {
      float w = __int_as_float(p[k].y);
      float2 f = h2f2(u[k]);
      acc0 += w * f.x;
      acc1 += w * f.y;
    }
  }
  for (; e < e1; e++) {
    int2 p0 = ew[e];
    float w0 = __int_as_float(p0.y);
    float2 f0 = h2f2(Ysrc[(size_t)p0.x * CPN + cp]);
    acc0 += w0 * f0.x;
    acc1 += w0 * f0.y;
  }
  Ydst[(size_t)i * CPN + cp] = packh2(acc0, acc1);
}

// ----------------- GroupNorm(8) + bias + ReLU (fp16 in/out) -----------------
template <int CPG>
__global__ __launch_bounds__(256) void k_gn(const unsigned short* __restrict__ src, const float* __restrict__ bias,
                                            const float* __restrict__ gamma, const float* __restrict__ beta,
                                            unsigned short* __restrict__ dst) {
  constexpr int C = CPG * 8;
  int t = blockIdx.x * 256 + threadIdx.x;   // (node, group); grid 5000*256 = NN*8 exact
  int i = t >> 3, g = t & 7;
  float v[CPG];
  const unsigned* p = reinterpret_cast<const unsigned*>(src + (size_t)i * C + g * CPG);
#pragma unroll
  for (int q = 0; q < CPG / 2; q++) {
    float2 f = h2f2(p[q]);
    v[2 * q] = f.x; v[2 * q + 1] = f.y;
  }
  float mean = 0.f;
#pragma unroll
  for (int c = 0; c < CPG; c++) { v[c] += bias[g * CPG + c]; mean += v[c]; }
  mean *= (1.f / CPG);
  float var = 0.f;
#pragma unroll
  for (int c = 0; c < CPG; c++) { float d = v[c] - mean; var += d * d; }
  var *= (1.f / CPG);
  float rs = rsqrtf(var + 1e-5f);
  unsigned* dp = reinterpret_cast<unsigned*>(dst + (size_t)i * C + g * CPG);
#pragma unroll
  for (int q = 0; q < CPG / 2; q++) {
    float o0 = fmaxf((v[2 * q] - mean) * rs * gamma[g * CPG + 2 * q] + beta[g * CPG + 2 * q], 0.f);
    float o1 = fmaxf((v[2 * q + 1] - mean) * rs * gamma[g * CPG + 2 * q + 1] + beta[g * CPG + 2 * q + 1], 0.f);
    dp[q] = packh2(o0, o1);
  }
}

// ----------------- Readout: (16 x 320000) @ (320000 x 128), 2-stage split-K ----------
__global__ __launch_bounds__(256) void k_final1(const unsigned short* __restrict__ h3,
                                                const float* __restrict__ Wl,
                                                float* __restrict__ part) {
  __shared__ float hs[16 * FD2];     // 16 KB
  __shared__ float red[2048];        // 8 KB
  int d0 = blockIdx.x * FD2;
  const unsigned* h3u = reinterpret_cast<const unsigned*>(h3);
  for (int idx = threadIdx.x; idx < 16 * (FD2 / 2); idx += 256) {
    int b = idx / (FD2 / 2), dq = idx % (FD2 / 2);
    float2 f = h2f2(h3u[(size_t)b * 160000 + (d0 >> 1) + dq]);
    hs[b * FD2 + 2 * dq] = f.x;
    hs[b * FD2 + 2 * dq + 1] = f.y;
  }
  __syncthreads();
  int w = threadIdx.x >> 6, lane = threadIdx.x & 63;
  float a0[16], a1[16];
#pragma unroll
  for (int b = 0; b < 16; b++) { a0[b] = 0.f; a1[b] = 0.f; }
  const float* wp = Wl + (size_t)(d0 + w * (FD2 / 4)) * 128 + 2 * lane;
#pragma unroll 2
  for (int r = 0; r < FD2 / 4; r++) {
    float2 wv = *reinterpret_cast<const float2*>(wp + (size_t)r * 128);
    int row = w * (FD2 / 4) + r;
#pragma unroll
    for (int b = 0; b < 16; b++) {
      float h = hs[b * FD2 + row];
      a0[b] += wv.x * h;
      a1[b] += wv.y * h;
    }
  }
  float2* red2 = reinterpret_cast<float2*>(red);
  for (int ww = 0; ww < 4; ww++) {
    if (w == ww) {
#pragma unroll
      for (int b = 0; b < 16; b++) {
        if (ww == 0) {
          red2[b * 64 + lane] = make_float2(a0[b], a1[b]);
        } else {
          float2 r2 = red2[b * 64 + lane];
          r2.x += a0[b]; r2.y += a1[b];
          red2[b * 64 + lane] = r2;
        }
      }
    }
    __syncthreads();
  }
  for (int i = threadIdx.x; i < 2048; i += 256)
    part[(size_t)blockIdx.x * 2048 + i] = red[i];
}

// Stage 2: 8 blocks x 256 threads; each thread reduces 1250 partials + bias.
__global__ __launch_bounds__(256) void k_final2(const float* __restrict__ part, const float* __restrict__ bl,
                                                float* __restrict__ out) {
  int o = blockIdx.x * 256 + threadIdx.x;   // 0..2047
  float s = bl[o & 127];
#pragma unroll 10
  for (int p = 0; p < 1250; p++) s += part[(size_t)p * 2048 + o];
  out[o] = s;
}

// ----------------- launcher -----------------
extern "C" void kernel_launch(void* const* d_in, const int* in_sizes, int n_in,
                              void* d_out, int out_size, void* d_ws, size_t ws_size,
                              hipStream_t stream) {
  const float* x   = (const float*)d_in[0];
  const int*   ei  = (const int*)d_in[1];   // harness stages ALL integer inputs as int32
  const float* W0  = (const float*)d_in[2];
  const float* b0  = (const float*)d_in[3];
  const float* g0  = (const float*)d_in[4];
  const float* be0 = (const float*)d_in[5];
  const float* W1  = (const float*)d_in[6];
  const float* b1  = (const float*)d_in[7];
  const float* g1  = (const float*)d_in[8];
  const float* be1 = (const float*)d_in[9];
  const float* W2  = (const float*)d_in[10];
  const float* b2  = (const float*)d_in[11];
  const float* g2  = (const float*)d_in[12];
  const float* be2 = (const float*)d_in[13];
  const float* Wl  = (const float*)d_in[14];
  const float* bl  = (const float*)d_in[15];
  float* out = (float*)d_out;
  (void)in_sizes; (void)n_in; (void)out_size; (void)ws_size;

  char* pw = (char*)d_ws;
  auto carve = [&](size_t bytes) -> void* {
    void* r = (void*)pw;
    pw += (bytes + 255) & ~(size_t)255;
    return r;
  };
  int*            bcur     = (int*)   carve((size_t)NBKT * 4);
  int*            bbase    = (int*)   carve((size_t)NBKT * 4);
  int*            rowStart = (int*)   carve((size_t)(NN + 1) * 4);
  float*          dis      = (float*) carve((size_t)NN * 4);
  int2*           ew       = (int2*)  carve((size_t)EE * 8);
  unsigned short* Cwt      = (unsigned short*)carve((size_t)384 * 128 * 2);
  unsigned short* TxAll    = (unsigned short*)carve((size_t)NN * 32 * 2);
  float*          A3       = (float*) carve((size_t)NN * 3 * 4);
  float*          B3       = (float*) carve((size_t)NN * 3 * 4);
  unsigned short* Hbuf     = (unsigned short*)carve((size_t)NN * 128 * 2);
  unsigned short* Ybuf     = (unsigned short*)carve((size_t)NN * 384 * 2);
  float*          part     = (float*) carve((size_t)1250 * 2048 * 4);
  unsigned*       stg      = (unsigned*)Ybuf;   // (625<<13)*4B = 20.5MB; Ybuf dead until layer0 GEMM

  // ---- CSR build: multisplit with LDS-only per-edge atomics ----
  k_binit<<<3, 256, 0, stream>>>(bcur);
  k_bucketA<<<ABLK, 256, 0, stream>>>(ei, bcur, stg);
  k_bktscan<<<1, 1024, 0, stream>>>(bcur, bbase, rowStart);
  k_bucketB1<<<NBKT, 256, 0, stream>>>(stg, bcur, bbase, rowStart, dis);
  k_bucketB2<<<NBKT, 256, 0, stream>>>(stg, bcur, rowStart, dis, ew);

  // ---- Layer 0 (3 -> 128): classic Chebyshev, TxAll (NN x 32 fp16, zero-pad) ----
  k_copyx<<<625, 256, 0, stream>>>(x, A3, TxAll);
  k_prop3<1><<<625, 256, 0, stream>>>(A3, B3, TxAll, 1, rowStart, ew);
  k_prop3<2><<<625, 256, 0, stream>>>(B3, A3, TxAll, 2, rowStart, ew);
  k_prop3<2><<<625, 256, 0, stream>>>(A3, B3, TxAll, 3, rowStart, ew);
  k_prop3<2><<<625, 256, 0, stream>>>(B3, A3, TxAll, 4, rowStart, ew);
  k_prop3<2><<<625, 256, 0, stream>>>(A3, B3, TxAll, 5, rowStart, ew);
  k_padW0<<<16, 256, 0, stream>>>(W0, Cwt);
  k_gemm<32, 128><<<dim3(2500, 2), 256, 0, stream>>>(TxAll, Cwt, Ybuf);
  k_gn<16><<<5000, 256, 0, stream>>>(Ybuf, b0, g0, be0, Hbuf);

  // ---- Layer 1 (128 -> 64): one MFMA GEMM + 5 Horner props in cout space ----
  k_combine<128, 64><<<192, 256, 0, stream>>>(W1, Cwt);
  k_gemm<128, 64><<<dim3(2500, 6), 256, 0, stream>>>(Hbuf, Cwt, Ybuf);
  for (int j = 4; j >= 0; j--)
    k_horner<32><<<20000, 256, 0, stream>>>((unsigned*)(Ybuf + (size_t)(j + 1) * NN * 64),
                                            (unsigned*)(Ybuf + (size_t)j * NN * 64), rowStart, ew);
  k_gn<8><<<5000, 256, 0, stream>>>(Ybuf, b1, g1, be1, Hbuf);

  // ---- Layer 2 (64 -> 32) ----
  k_combine<64, 32><<<48, 256, 0, stream>>>(W2, Cwt);
  k_gemm<64, 32><<<dim3(2500, 3), 256, 0, stream>>>(Hbuf, Cwt, Ybuf);
  for (int j = 4; j >= 0; j--)
    k_horner<16><<<10000, 256, 0, stream>>>((unsigned*)(Ybuf + (size_t)(j + 1) * NN * 32),
                                            (unsigned*)(Ybuf + (size_t)j * NN * 32), rowStart, ew);
  k_gn<4><<<5000, 256, 0, stream>>>(Ybuf, b2, g2, be2, Hbuf);

  // ---- Readout: 2-stage split-K ----
  k_final1<<<1250, 256, 0, stream>>>(Hbuf, Wl, part);
  k_final2<<<8, 256, 0, stream>>>(part, bl, out);
}

// Round 5
// 1222.668 us; speedup vs baseline: 1.2139x; 1.0477x over previous
//
#include <hip/hip_runtime.h>
#include <hip/hip_fp16.h>

// GraphEncoder: 3x ChebConv(K=6) + GroupNorm(8)/ReLU + dense readout.
// R10: top-5 now dominated by the harness's 93us/655MB workspace re-poison
//      (fillBufferAligned) -> our kernels all <93us; model says launch count
//      (33) + edge-stream bytes are first-order. Changes (numerics-preserving):
//      (1) 4B edge records c|(deg_c<<18); w reconstructed bit-exactly as
//          -dis[i]*rsqrtf(deg_c) -> halves edge stream in all 15 passes;
//      (2) k_prep mega-kernel (bcur init + padW0 + 2x combine + copyx);
//          bktscan folded into B1 (per-block 625-entry prefix);
//      (3) GroupNorm fused: layer0 into gemm epilogue (16-lane shfl stats),
//          layers 1/2 into the last Horner pass (4/2-lane shfl stats).
//      33 -> 24 dispatches, ~-280MB HBM.
// R9: per-bucket LDS degree histogram (no global per-edge atomics).
// R6: two-phase bucket multisplit. R5: split-K readout. R4: fp16 + fp32 accum.

#define NN 160000
#define EE 2560000
#define FD2 256
#define NBKT 625          // buckets of 256 rows each (NN = 625*256)
#define BCAPL 13          // bucket capacity 8192 = 1<<13 (mean fill 4096)
#define ABLK 500          // phase-A blocks
#define EPT 20            // edges per thread: 500*256*20 = EE exact

typedef __attribute__((ext_vector_type(8))) _Float16 half8;
typedef __attribute__((ext_vector_type(4))) float floatx4;

__device__ inline float2 h2f2(unsigned u) {
  __half2 h = __builtin_bit_cast(__half2, u);
  return __half22float2(h);
}
__device__ inline unsigned short f2h(float f) {
  return __builtin_bit_cast(unsigned short, __float2half_rn(f));
}
__device__ inline unsigned packh2(float a, float b) {
  return __builtin_bit_cast(unsigned, __floats2half2_rn(a, b));
}

// ----------------- weight prep (device helper for k_prep) -----------------
template <int CIN, int COUT>
__device__ inline void combine_item(const float* __restrict__ W, unsigned short* __restrict__ Bt, int idx) {
  int co = idx % COUT;
  int j  = (idx / COUT) % 6;
  int ci = idx / (6 * COUT);
  float c0, c1, c2, c3, c4, c5;
  switch (j) {
    case 0:  c0 = 1;  c1 = 0;  c2 = -1; c3 = 0;   c4 = 1;  c5 = 0;   break;
    case 1:  c0 = 0;  c1 = 1;  c2 = 0;  c3 = -3;  c4 = 0;  c5 = 5;   break;
    case 2:  c0 = 0;  c1 = 0;  c2 = 2;  c3 = 0;   c4 = -8; c5 = 0;   break;
    case 3:  c0 = 0;  c1 = 0;  c2 = 0;  c3 = 4;   c4 = 0;  c5 = -20; break;
    case 4:  c0 = 0;  c1 = 0;  c2 = 0;  c3 = 0;   c4 = 8;  c5 = 0;   break;
    default: c0 = 0;  c1 = 0;  c2 = 0;  c3 = 0;   c4 = 0;  c5 = 16;  break;
  }
  float s = 0.f;
  s += c0 * W[(0 * CIN + ci) * COUT + co];
  s += c1 * W[(1 * CIN + ci) * COUT + co];
  s += c2 * W[(2 * CIN + ci) * COUT + co];
  s += c3 * W[(3 * CIN + ci) * COUT + co];
  s += c4 * W[(4 * CIN + ci) * COUT + co];
  s += c5 * W[(5 * CIN + ci) * COUT + co];
  Bt[(j * COUT + co) * CIN + ci] = f2h(s);
}

// Mega-prep: bcur init + W0 pad + combine(W1) + combine(W2) + copyx/TxAll.
// All ranges independent; grid 884*256 covers 625+4096+49152+12288+160000.
__global__ __launch_bounds__(256) void k_prep(const float* __restrict__ W0, const float* __restrict__ W1,
                                              const float* __restrict__ W2, const float* __restrict__ x,
                                              int* __restrict__ bcur, unsigned short* __restrict__ Cwt0,
                                              unsigned short* __restrict__ Cwt1, unsigned short* __restrict__ Cwt2,
                                              float* __restrict__ A3, unsigned short* __restrict__ TxAll) {
  int idx = blockIdx.x * 256 + threadIdx.x;
  if (idx < NBKT) { bcur[idx] = idx << BCAPL; return; }
  idx -= NBKT;
  if (idx < 128 * 32) {   // W0 (18x128) -> transposed padded fp16 (128x32)
    int co = idx >> 5, t = idx & 31;
    Cwt0[co * 32 + t] = (t < 18) ? f2h(W0[t * 128 + co]) : (unsigned short)0;
    return;
  }
  idx -= 128 * 32;
  if (idx < 128 * 6 * 64) { combine_item<128, 64>(W1, Cwt1, idx); return; }
  idx -= 128 * 6 * 64;
  if (idx < 64 * 6 * 32) { combine_item<64, 32>(W2, Cwt2, idx); return; }
  idx -= 64 * 6 * 32;
  if (idx < NN) {          // copyx: A3 + zero-padded 64B TxAll row
    int i = idx;
    float v0 = x[i * 3], v1 = x[i * 3 + 1], v2 = x[i * 3 + 2];
    A3[i * 3] = v0; A3[i * 3 + 1] = v1; A3[i * 3 + 2] = v2;
    uint4* dst = reinterpret_cast<uint4*>(TxAll + (size_t)i * 32);
    uint4 z = make_uint4(0u, 0u, 0u, 0u);
    dst[0] = make_uint4(packh2(v0, v1), (unsigned)f2h(v2), 0u, 0u);
    dst[1] = z; dst[2] = z; dst[3] = z;
  }
}

// ----------------- CSR build (atomic-free-global multisplit) -----------------
// Phase A: 500 blocks x 256 thr x 20 edges. LDS bucket histogram, reserve
// one contiguous staging run per (block,bucket), scatter packed 4B entries
// (r&255)<<18 | c. Global atomics: only 625 bcur adds per block.
__global__ __launch_bounds__(256) void k_bucketA(const int* __restrict__ ei,
                                                 int* __restrict__ bcur, unsigned* __restrict__ stg) {
  __shared__ int bcnt[NBKT];
  __shared__ int gbase[NBKT];
  int tid = threadIdx.x;
  for (int i = tid; i < NBKT; i += 256) bcnt[i] = 0;
  __syncthreads();
  int r[EPT];
  int e0 = blockIdx.x * (256 * EPT);
#pragma unroll
  for (int k = 0; k < EPT; k++) {
    int e = e0 + k * 256 + tid;
    r[k] = ei[e];
    atomicAdd(&bcnt[r[k] >> 8], 1);
  }
  __syncthreads();
  for (int i = tid; i < NBKT; i += 256) {
    gbase[i] = atomicAdd(&bcur[i], bcnt[i]);
    bcnt[i] = 0;
  }
  __syncthreads();
#pragma unroll
  for (int k = 0; k < EPT; k++) {
    int e = e0 + k * 256 + tid;
    int c = ei[EE + e];
    int b = r[k] >> 8;
    int off = atomicAdd(&bcnt[b], 1);
    int pos = gbase[b] + off;
    if (pos < ((b + 1) << BCAPL))    // ~60-sigma overflow guard
      stg[pos] = ((unsigned)(r[k] & 255) << 18) | (unsigned)c;
  }
}

// Phase B1: per bucket: inline prefix over 625 bucket totals (bbase), LDS
// degree histogram + scan -> rowStart, dis, deg for its 256 rows.
__global__ __launch_bounds__(256) void k_bucketB1(const unsigned* __restrict__ stg, const int* __restrict__ bcur,
                                                  int* __restrict__ rowStart, float* __restrict__ dis,
                                                  int* __restrict__ deg) {
  __shared__ int degl[256];
  __shared__ int s[256];
  __shared__ int red[256];
  int b = blockIdx.x;
  int tid = threadIdx.x;
  int part = 0;
  for (int j = tid; j < NBKT; j += 256) {
    int cj = bcur[j] - (j << BCAPL);
    if (cj > (1 << BCAPL)) cj = 1 << BCAPL;
    if (j < b) part += cj;
  }
  red[tid] = part;
  degl[tid] = 0;
  __syncthreads();
  for (int off = 128; off > 0; off >>= 1) {
    if (tid < off) red[tid] += red[tid + off];
    __syncthreads();
  }
  int bbase = red[0];
  int cnt = bcur[b] - (b << BCAPL);
  if (cnt > (1 << BCAPL)) cnt = 1 << BCAPL;
  int base = b << BCAPL;
  for (int k = tid; k < cnt; k += 256)
    atomicAdd(&degl[stg[base + k] >> 18], 1);
  __syncthreads();
  int d = degl[tid];
  s[tid] = d;
  __syncthreads();
  for (int off = 1; off < 256; off <<= 1) {
    int t = (tid >= off) ? s[tid - off] : 0;
    __syncthreads();
    s[tid] += t;
    __syncthreads();
  }
  int r0 = b << 8;
  rowStart[r0 + tid] = bbase + s[tid] - d;
  dis[r0 + tid] = d > 0 ? rsqrtf((float)d) : 0.f;
  deg[r0 + tid] = d;
  if (b == 0 && tid == 0) rowStart[NN] = EE;
}

// Phase B2: per bucket: LDS row-cursors; 4B (c | deg_c<<18) scatter into the
// bucket's ~16KB L2-resident CSR window. deg[c] gather is L2-resident (640KB).
__global__ __launch_bounds__(256) void k_bucketB2(const unsigned* __restrict__ stg, const int* __restrict__ bcur,
                                                  const int* __restrict__ rowStart, const int* __restrict__ deg,
                                                  unsigned* __restrict__ ewc) {
  __shared__ int curs[256];
  int b = blockIdx.x;
  int tid = threadIdx.x;
  int r0 = b << 8;
  curs[tid] = rowStart[r0 + tid];
  __syncthreads();
  int cnt = bcur[b] - (b << BCAPL);
  if (cnt > (1 << BCAPL)) cnt = 1 << BCAPL;
  int base = b << BCAPL;
  for (int k = tid; k < cnt; k += 256) {
    unsigned u = stg[base + k];
    int rlow = u >> 18;
    int c = u & 0x3FFFFu;
    int pos = atomicAdd(&curs[rlow], 1);
    int dc = deg[c];
    if (dc > 8191) dc = 8191;   // 13-bit field; P(deg>8191) ~ 0
    ewc[pos] = (unsigned)c | ((unsigned)dc << 18);
  }
}

// ----------------- Layer 0 (cin=3) classic Chebyshev -----------------
// w reconstructed per edge: w = -dis[i] * rsqrtf(deg_c)  (bit-identical ops).
template <int MODE>   // 1: Tx1 = prop(Tx0); 2: Tnew = 2*prop(Tsrc) - Tdst (in place)
__global__ __launch_bounds__(256) void k_prop3(const float* __restrict__ Tsrc, float* __restrict__ Tdst,
                                               unsigned short* __restrict__ TxAll, int ks,
                                               const int* __restrict__ rowStart, const unsigned* __restrict__ ewc,
                                               const float* __restrict__ dis) {
  int i = blockIdx.x * 256 + threadIdx.x;
  if (i >= NN) return;
  float s0 = 0.f, s1 = 0.f, s2 = 0.f;
  int e = rowStart[i], e1 = rowStart[i + 1];
  for (; e + 3 < e1; e += 4) {
    unsigned u0 = ewc[e], u1 = ewc[e + 1], u2 = ewc[e + 2], u3 = ewc[e + 3];
    int c0 = u0 & 0x3FFFFu, c1 = u1 & 0x3FFFFu, c2 = u2 & 0x3FFFFu, c3 = u3 & 0x3FFFFu;
    unsigned d0 = u0 >> 18, d1 = u1 >> 18, d2 = u2 >> 18, d3 = u3 >> 18;
    float w0 = d0 ? rsqrtf((float)d0) : 0.f;
    float w1 = d1 ? rsqrtf((float)d1) : 0.f;
    float w2 = d2 ? rsqrtf((float)d2) : 0.f;
    float w3 = d3 ? rsqrtf((float)d3) : 0.f;
    s0 += w0 * Tsrc[c0 * 3] + w1 * Tsrc[c1 * 3] + w2 * Tsrc[c2 * 3] + w3 * Tsrc[c3 * 3];
    s1 += w0 * Tsrc[c0 * 3 + 1] + w1 * Tsrc[c1 * 3 + 1] + w2 * Tsrc[c2 * 3 + 1] + w3 * Tsrc[c3 * 3 + 1];
    s2 += w0 * Tsrc[c0 * 3 + 2] + w1 * Tsrc[c1 * 3 + 2] + w2 * Tsrc[c2 * 3 + 2] + w3 * Tsrc[c3 * 3 + 2];
  }
  for (; e < e1; e++) {
    unsigned u0 = ewc[e];
    int c0 = u0 & 0x3FFFFu;
    unsigned d0 = u0 >> 18;
    float w0 = d0 ? rsqrtf((float)d0) : 0.f;
    s0 += w0 * Tsrc[c0 * 3];
    s1 += w0 * Tsrc[c0 * 3 + 1];
    s2 += w0 * Tsrc[c0 * 3 + 2];
  }
  float ndr = -dis[i];
  float a0 = ndr * s0, a1 = ndr * s1, a2 = ndr * s2;
  if (MODE == 2) {
    a0 = 2.f * a0 - Tdst[i * 3];
    a1 = 2.f * a1 - Tdst[i * 3 + 1];
    a2 = 2.f * a2 - Tdst[i * 3 + 2];
  }
  Tdst[i * 3] = a0; Tdst[i * 3 + 1] = a1; Tdst[i * 3 + 2] = a2;
  unsigned short* tp = TxAll + i * 32 + ks * 3;
  tp[0] = f2h(a0); tp[1] = f2h(a1); tp[2] = f2h(a2);
}

// ----------------- Layer-0 GEMM (K=32, COUT=128) + fused GroupNorm ----------
// One block = 64 rows x all 128 cols. Group g = col-block cb (16 ch) -> stats
// via 16-lane shfl_xor butterfly. Writes gn'd fp16 straight to Hbuf.
__global__ __launch_bounds__(256) void k_gemm0gn(const unsigned short* __restrict__ A,
                                                 const unsigned short* __restrict__ Bt,
                                                 const float* __restrict__ bias, const float* __restrict__ gamma,
                                                 const float* __restrict__ beta, unsigned short* __restrict__ H) {
  constexpr int KP = 40;
  __shared__ unsigned short As[64 * KP];
  __shared__ unsigned short Bs[128 * KP];
  __shared__ float pb[128], pg[128], pe[128];
  int i0 = blockIdx.x * 64;
  for (int idx = threadIdx.x; idx < 64 * 4; idx += 256) {
    int row = idx >> 2, seg = idx & 3;
    uint4 v = ((const uint4*)A)[(size_t)(i0 + row) * 4 + seg];
    *reinterpret_cast<uint4*>(&As[row * KP + seg * 8]) = v;
  }
  for (int idx = threadIdx.x; idx < 128 * 4; idx += 256) {
    int row = idx >> 2, seg = idx & 3;
    uint4 v = ((const uint4*)Bt)[(size_t)row * 4 + seg];
    *reinterpret_cast<uint4*>(&Bs[row * KP + seg * 8]) = v;
  }
  if (threadIdx.x < 128) {
    pb[threadIdx.x] = bias[threadIdx.x];
    pg[threadIdx.x] = gamma[threadIdx.x];
    pe[threadIdx.x] = beta[threadIdx.x];
  }
  __syncthreads();
  int w = threadIdx.x >> 6, lane = threadIdx.x & 63;
  int mn = lane & 15, q = lane >> 4;
  floatx4 acc[8];
#pragma unroll
  for (int cb = 0; cb < 8; cb++) acc[cb] = {0.f, 0.f, 0.f, 0.f};
  half8 af = *reinterpret_cast<const half8*>(&As[(16 * w + mn) * KP + q * 8]);
#pragma unroll
  for (int cb = 0; cb < 8; cb++) {
    half8 bf = *reinterpret_cast<const half8*>(&Bs[(cb * 16 + mn) * KP + q * 8]);
    acc[cb] = __builtin_amdgcn_mfma_f32_16x16x32_f16(af, bf, acc[cb], 0, 0, 0);
  }
  // epilogue: per col-block (= one 16-channel group), stats across 16 mn lanes
#pragma unroll
  for (int cb = 0; cb < 8; cb++) {
    int ch = cb * 16 + mn;
    float bs = pb[ch], ga = pg[ch], be = pe[ch];
    float v[4], S[4];
#pragma unroll
    for (int r = 0; r < 4; r++) { v[r] = acc[cb][r] + bs; S[r] = v[r]; }
#pragma unroll
    for (int m = 1; m < 16; m <<= 1)
#pragma unroll
      for (int r = 0; r < 4; r++) S[r] += __shfl_xor(S[r], m);
    float d[4], Q[4];
#pragma unroll
    for (int r = 0; r < 4; r++) { d[r] = v[r] - S[r] * 0.0625f; Q[r] = d[r] * d[r]; }
#pragma unroll
    for (int m = 1; m < 16; m <<= 1)
#pragma unroll
      for (int r = 0; r < 4; r++) Q[r] += __shfl_xor(Q[r], m);
#pragma unroll
    for (int r = 0; r < 4; r++) {
      float rs = rsqrtf(Q[r] * 0.0625f + 1e-5f);
      int i = i0 + 16 * w + q * 4 + r;
      H[(size_t)i * 128 + ch] = f2h(fmaxf(d[r] * rs * ga + be, 0.f));
    }
  }
}

// ----------------- MFMA f16 GEMM: (N x KDIM) @ Bt(ncol x KDIM)^T -> Y fp16 ----------
template <int KDIM, int COUT>
__global__ __launch_bounds__(256) void k_gemm(const unsigned short* __restrict__ A,
                                              const unsigned short* __restrict__ Bt,
                                              unsigned short* __restrict__ Y) {
  constexpr int KP = KDIM + 8;
  __shared__ unsigned short As[64 * KP];
  __shared__ unsigned short Bs[64 * KP];
  int i0 = blockIdx.x * 64;
  int c0 = blockIdx.y * 64;
  for (int idx = threadIdx.x; idx < 64 * (KDIM / 8); idx += 256) {
    int row = idx / (KDIM / 8), seg = idx % (KDIM / 8);
    uint4 v = ((const uint4*)A)[(size_t)(i0 + row) * (KDIM / 8) + seg];
    *reinterpret_cast<uint4*>(&As[row * KP + seg * 8]) = v;
  }
  for (int idx = threadIdx.x; idx < 64 * (KDIM / 8); idx += 256) {
    int row = idx / (KDIM / 8), seg = idx % (KDIM / 8);
    uint4 v = ((const uint4*)Bt)[(size_t)(c0 + row) * (KDIM / 8) + seg];
    *reinterpret_cast<uint4*>(&Bs[row * KP + seg * 8]) = v;
  }
  __syncthreads();
  int w = threadIdx.x >> 6, lane = threadIdx.x & 63;
  int mn = lane & 15, q = lane >> 4;
  floatx4 acc[4];
#pragma unroll
  for (int cb = 0; cb < 4; cb++) acc[cb] = {0.f, 0.f, 0.f, 0.f};
#pragma unroll
  for (int ks = 0; ks < KDIM / 32; ks++) {
    half8 af = *reinterpret_cast<const half8*>(&As[(16 * w + mn) * KP + ks * 32 + q * 8]);
#pragma unroll
    for (int cb = 0; cb < 4; cb++) {
      half8 bf = *reinterpret_cast<const half8*>(&Bs[(cb * 16 + mn) * KP + ks * 32 + q * 8]);
      acc[cb] = __builtin_amdgcn_mfma_f32_16x16x32_f16(af, bf, acc[cb], 0, 0, 0);
    }
  }
  // C/D layout: col = lane&15, row = (lane>>4)*4 + reg  [m89; dtype-independent]
#pragma unroll
  for (int cb = 0; cb < 4; cb++) {
    int jc = c0 + cb * 16 + mn;
    int slice = jc / COUT, cc = jc % COUT;
    unsigned short* dst = Y + (size_t)slice * NN * COUT + cc;
#pragma unroll
    for (int r = 0; r < 4; r++) {
      int i = i0 + 16 * w + q * 4 + r;
      dst[(size_t)i * COUT] = f2h(acc[cb][r]);
    }
  }
}

// ----------------- Horner prop step (fp16), optional fused GroupNorm --------
// FUSE=1 (last pass): add bias, group stats via shfl_xor over CPN/8 lanes,
// gn+relu, write to dst (Hbuf) instead of Ydst.
template <int CPN, int FUSE>
__global__ __launch_bounds__(256) void k_horner(const unsigned* __restrict__ Ysrc, unsigned* __restrict__ Ydst,
                                                const int* __restrict__ rowStart, const unsigned* __restrict__ ewc,
                                                const float* __restrict__ dis, unsigned* __restrict__ dst,
                                                const float* __restrict__ bias, const float* __restrict__ gamma,
                                                const float* __restrict__ beta) {
  int t = blockIdx.x * 256 + threadIdx.x;
  int i = t / CPN;
  int cp = t % CPN;
  float2 a = h2f2(Ydst[(size_t)i * CPN + cp]);
  float s0 = 0.f, s1 = 0.f;
  int e = rowStart[i], e1 = rowStart[i + 1];
  for (; e + 7 < e1; e += 8) {
    unsigned uu[8], u[8];
    float wv[8];
#pragma unroll
    for (int k = 0; k < 8; k++) uu[k] = ewc[e + k];
#pragma unroll
    for (int k = 0; k < 8; k++) u[k] = Ysrc[(size_t)(uu[k] & 0x3FFFFu) * CPN + cp];
#pragma unroll
    for (int k = 0; k < 8; k++) {
      unsigned dc = uu[k] >> 18;
      wv[k] = dc ? rsqrtf((float)dc) : 0.f;
    }
#pragma unroll
    for (int k = 0; k < 8; k++) {
      float2 f = h2f2(u[k]);
      s0 += wv[k] * f.x;
      s1 += wv[k] * f.y;
    }
  }
  for (; e < e1; e++) {
    unsigned u0 = ewc[e];
    unsigned dc = u0 >> 18;
    float w0 = dc ? rsqrtf((float)dc) : 0.f;
    float2 f0 = h2f2(Ysrc[(size_t)(u0 & 0x3FFFFu) * CPN + cp]);
    s0 += w0 * f0.x;
    s1 += w0 * f0.y;
  }
  float ndr = -dis[i];
  float v0 = a.x + ndr * s0, v1 = a.y + ndr * s1;
  if (FUSE == 0) {
    Ydst[(size_t)i * CPN + cp] = packh2(v0, v1);
  } else {
    constexpr int CPG = CPN / 4;   // channels per group (C = 2*CPN, G = 8)
    constexpr int LPG = CPN / 8;   // lanes per group
    v0 += bias[2 * cp];
    v1 += bias[2 * cp + 1];
    float s = v0 + v1;
#pragma unroll
    for (int m = 1; m < LPG; m <<= 1) s += __shfl_xor(s, m);
    float mean = s * (1.0f / CPG);
    float d0 = v0 - mean, d1 = v1 - mean;
    float qq = d0 * d0 + d1 * d1;
#pragma unroll
    for (int m = 1; m < LPG; m <<= 1) qq += __shfl_xor(qq, m);
    float rs = rsqrtf(qq * (1.0f / CPG) + 1e-5f);
    float o0 = fmaxf(d0 * rs * gamma[2 * cp] + beta[2 * cp], 0.f);
    float o1 = fmaxf(d1 * rs * gamma[2 * cp + 1] + beta[2 * cp + 1], 0.f);
    dst[(size_t)i * CPN + cp] = packh2(o0, o1);
  }
}

// ----------------- Readout: (16 x 320000) @ (320000 x 128), 2-stage split-K ----------
__global__ __launch_bounds__(256) void k_final1(const unsigned short* __restrict__ h3,
                                                const float* __restrict__ Wl,
                                                float* __restrict__ part) {
  __shared__ float hs[16 * FD2];     // 16 KB
  __shared__ float red[2048];        // 8 KB
  int d0 = blockIdx.x * FD2;
  const unsigned* h3u = reinterpret_cast<const unsigned*>(h3);
  for (int idx = threadIdx.x; idx < 16 * (FD2 / 2); idx += 256) {
    int b = idx / (FD2 / 2), dq = idx % (FD2 / 2);
    float2 f = h2f2(h3u[(size_t)b * 160000 + (d0 >> 1) + dq]);
    hs[b * FD2 + 2 * dq] = f.x;
    hs[b * FD2 + 2 * dq + 1] = f.y;
  }
  __syncthreads();
  int w = threadIdx.x >> 6, lane = threadIdx.x & 63;
  float a0[16], a1[16];
#pragma unroll
  for (int b = 0; b < 16; b++) { a0[b] = 0.f; a1[b] = 0.f; }
  const float* wp = Wl + (size_t)(d0 + w * (FD2 / 4)) * 128 + 2 * lane;
#pragma unroll 2
  for (int r = 0; r < FD2 / 4; r++) {
    float2 wv = *reinterpret_cast<const float2*>(wp + (size_t)r * 128);
    int row = w * (FD2 / 4) + r;
#pragma unroll
    for (int b = 0; b < 16; b++) {
      float h = hs[b * FD2 + row];
      a0[b] += wv.x * h;
      a1[b] += wv.y * h;
    }
  }
  float2* red2 = reinterpret_cast<float2*>(red);
  for (int ww = 0; ww < 4; ww++) {
    if (w == ww) {
#pragma unroll
      for (int b = 0; b < 16; b++) {
        if (ww == 0) {
          red2[b * 64 + lane] = make_float2(a0[b], a1[b]);
        } else {
          float2 r2 = red2[b * 64 + lane];
          r2.x += a0[b]; r2.y += a1[b];
          red2[b * 64 + lane] = r2;
        }
      }
    }
    __syncthreads();
  }
  for (int i = threadIdx.x; i < 2048; i += 256)
    part[(size_t)blockIdx.x * 2048 + i] = red[i];
}

// Stage 2: 8 blocks x 256 threads; each thread reduces 1250 partials + bias.
__global__ __launch_bounds__(256) void k_final2(const float* __restrict__ part, const float* __restrict__ bl,
                                                float* __restrict__ out) {
  int o = blockIdx.x * 256 + threadIdx.x;   // 0..2047
  float s = bl[o & 127];
#pragma unroll 10
  for (int p = 0; p < 1250; p++) s += part[(size_t)p * 2048 + o];
  out[o] = s;
}

// ----------------- launcher -----------------
extern "C" void kernel_launch(void* const* d_in, const int* in_sizes, int n_in,
                              void* d_out, int out_size, void* d_ws, size_t ws_size,
                              hipStream_t stream) {
  const float* x   = (const float*)d_in[0];
  const int*   ei  = (const int*)d_in[1];   // harness stages ALL integer inputs as int32
  const float* W0  = (const float*)d_in[2];
  const float* b0  = (const float*)d_in[3];
  const float* g0  = (const float*)d_in[4];
  const float* be0 = (const float*)d_in[5];
  const float* W1  = (const float*)d_in[6];
  const float* b1  = (const float*)d_in[7];
  const float* g1  = (const float*)d_in[8];
  const float* be1 = (const float*)d_in[9];
  const float* W2  = (const float*)d_in[10];
  const float* b2  = (const float*)d_in[11];
  const float* g2  = (const float*)d_in[12];
  const float* be2 = (const float*)d_in[13];
  const float* Wl  = (const float*)d_in[14];
  const float* bl  = (const float*)d_in[15];
  float* out = (float*)d_out;
  (void)in_sizes; (void)n_in; (void)out_size; (void)ws_size;

  char* pw = (char*)d_ws;
  auto carve = [&](size_t bytes) -> void* {
    void* r = (void*)pw;
    pw += (bytes + 255) & ~(size_t)255;
    return r;
  };
  int*            bcur     = (int*)   carve((size_t)NBKT * 4);
  int*            rowStart = (int*)   carve((size_t)(NN + 1) * 4);
  float*          dis      = (float*) carve((size_t)NN * 4);
  int*            deg      = (int*)   carve((size_t)NN * 4);
  unsigned*       ewc      = (unsigned*)carve((size_t)EE * 4);
  unsigned short* Cwt0     = (unsigned short*)carve((size_t)128 * 32 * 2);
  unsigned short* Cwt1     = (unsigned short*)carve((size_t)384 * 128 * 2);
  unsigned short* Cwt2     = (unsigned short*)carve((size_t)192 * 64 * 2);
  unsigned short* TxAll    = (unsigned short*)carve((size_t)NN * 32 * 2);
  float*          A3       = (float*) carve((size_t)NN * 3 * 4);
  float*          B3       = (float*) carve((size_t)NN * 3 * 4);
  unsigned short* Hbuf     = (unsigned short*)carve((size_t)NN * 128 * 2);
  unsigned short* Ybuf     = (unsigned short*)carve((size_t)NN * 384 * 2);
  float*          part     = (float*) carve((size_t)1250 * 2048 * 4);
  unsigned*       stg      = (unsigned*)Ybuf;   // (625<<13)*4B = 20.5MB; Ybuf dead until layer1 GEMM

  // ---- prep (weights + bcur + copyx) and CSR build ----
  k_prep<<<884, 256, 0, stream>>>(W0, W1, W2, x, bcur, Cwt0, Cwt1, Cwt2, A3, TxAll);
  k_bucketA<<<ABLK, 256, 0, stream>>>(ei, bcur, stg);
  k_bucketB1<<<NBKT, 256, 0, stream>>>(stg, bcur, rowStart, dis, deg);
  k_bucketB2<<<NBKT, 256, 0, stream>>>(stg, bcur, rowStart, deg, ewc);

  // ---- Layer 0 (3 -> 128): classic Chebyshev; GEMM with fused GroupNorm ----
  k_prop3<1><<<625, 256, 0, stream>>>(A3, B3, TxAll, 1, rowStart, ewc, dis);
  k_prop3<2><<<625, 256, 0, stream>>>(B3, A3, TxAll, 2, rowStart, ewc, dis);
  k_prop3<2><<<625, 256, 0, stream>>>(A3, B3, TxAll, 3, rowStart, ewc, dis);
  k_prop3<2><<<625, 256, 0, stream>>>(B3, A3, TxAll, 4, rowStart, ewc, dis);
  k_prop3<2><<<625, 256, 0, stream>>>(A3, B3, TxAll, 5, rowStart, ewc, dis);
  k_gemm0gn<<<2500, 256, 0, stream>>>(TxAll, Cwt0, b0, g0, be0, Hbuf);

  // ---- Layer 1 (128 -> 64): GEMM + 4 Horner props + fused(gn) last pass ----
  k_gemm<128, 64><<<dim3(2500, 6), 256, 0, stream>>>(Hbuf, Cwt1, Ybuf);
  for (int j = 4; j >= 1; j--)
    k_horner<32, 0><<<20000, 256, 0, stream>>>((unsigned*)(Ybuf + (size_t)(j + 1) * NN * 64),
                                               (unsigned*)(Ybuf + (size_t)j * NN * 64), rowStart, ewc, dis,
                                               nullptr, nullptr, nullptr, nullptr);
  k_horner<32, 1><<<20000, 256, 0, stream>>>((unsigned*)(Ybuf + (size_t)NN * 64),
                                             (unsigned*)Ybuf, rowStart, ewc, dis,
                                             (unsigned*)Hbuf, b1, g1, be1);

  // ---- Layer 2 (64 -> 32) ----
  k_gemm<64, 32><<<dim3(2500, 3), 256, 0, stream>>>(Hbuf, Cwt2, Ybuf);
  for (int j = 4; j >= 1; j--)
    k_horner<16, 0><<<10000, 256, 0, stream>>>((unsigned*)(Ybuf + (size_t)(j + 1) * NN * 32),
                                               (unsigned*)(Ybuf + (size_t)j * NN * 32), rowStart, ewc, dis,
                                               nullptr, nullptr, nullptr, nullptr);
  k_horner<16, 1><<<10000, 256, 0, stream>>>((unsigned*)(Ybuf + (size_t)NN * 32),
                                             (unsigned*)Ybuf, rowStart, ewc, dis,
                                             (unsigned*)Hbuf, b2, g2, be2);

  // ---- Readout: 2-stage split-K ----
  k_final1<<<1250, 256, 0, stream>>>(Hbuf, Wl, part);
  k_final2<<<8, 256, 0, stream>>>(part, bl, out);
}